// Round 10
// baseline (910.125 us; speedup 1.0000x reference)
//
#include <hip/hip_runtime.h>
#include <math.h>

// Problem constants
#define BATCH 16
#define HH 1024
#define WW 1024
#define TSTR 72          // padded LDS row stride (no pow2 stride)
#define NBLK 4096        // 16 images * 16x16 tiles of 64x64
#define NB0 1024         // pass0 blocks (64 per image)
#define NTOT 16777216.0  // 16*1024*1024

__device__ __forceinline__ float sigmf(float x) { return 1.0f / (1.0f + __expf(-x)); }

__device__ __forceinline__ double wredd(double v) {
#pragma unroll
    for (int o = 32; o; o >>= 1) v += __shfl_down(v, o, 64);
    return v;
}
__device__ __forceinline__ float wredminf(float v) {
#pragma unroll
    for (int o = 32; o; o >>= 1) v = fminf(v, __shfl_down(v, o, 64));
    return v;
}
__device__ __forceinline__ float wredmaxf(float v) {
#pragma unroll
    for (int o = 32; o; o >>= 1) v = fmaxf(v, __shfl_down(v, o, 64));
    return v;
}

// ---------------------------------------------------------------------------
// Pass 0: stream dem, per-image sum / sumsq partials (float4 loads).
// Block b handles image b>>6, sub-chunk b&63 (16384 floats).
// ---------------------------------------------------------------------------
__global__ __launch_bounds__(256) void pass0_kernel(
    const float* __restrict__ dem, double* __restrict__ pD0)
{
    const int blk = blockIdx.x;
    const int tid = threadIdx.x;
    const float4* __restrict__ p =
        (const float4*)(dem + (size_t)blk * 16384);
    double s = 0.0, ss = 0.0;
    for (int i = tid; i < 4096; i += 256) {
        float4 v = p[i];
        s  += (double)v.x + (double)v.y + (double)v.z + (double)v.w;
        ss += (double)v.x * v.x + (double)v.y * v.y
            + (double)v.z * v.z + (double)v.w * v.w;
    }
    s = wredd(s); ss = wredd(ss);
    __shared__ double sh[2][4];
    const int lane = tid & 63, w = tid >> 6;
    if (lane == 0) { sh[0][w] = s; sh[1][w] = ss; }
    __syncthreads();
    if (tid == 0) {
        pD0[blk]        = sh[0][0] + sh[0][1] + sh[0][2] + sh[0][3];
        pD0[NB0 + blk]  = sh[1][0] + sh[1][1] + sh[1][2] + sh[1][3];
    }
}

// ---------------------------------------------------------------------------
// Reduce 0: per-image mean and 1/(std+eps) (unbiased std), into RF.
// RF[0..15]=mean, RF[16..31]=istd. One wave.
// ---------------------------------------------------------------------------
__global__ __launch_bounds__(64) void reduce0_kernel(
    const double* __restrict__ pD0, float* __restrict__ RF)
{
    const int t = threadIdx.x;
    if (t < 16) {
        double s = 0.0, ss = 0.0;
        for (int j = 0; j < 64; j++) {
            s  += pD0[t * 64 + j];
            ss += pD0[NB0 + t * 64 + j];
        }
        const double NPI = 1048576.0;
        double mean = s / NPI;
        double var = (ss - s * s / NPI) / (NPI - 1.0);
        if (var < 0.0) var = 0.0;
        RF[t]      = (float)mean;
        RF[16 + t] = (float)(1.0 / (sqrt(var) + 1e-8));
    }
}

// ---------------------------------------------------------------------------
// Pass 1: per 64x64 tile (the only conv pass):
//  Stage A (target, halo3): box->edges->dilate->erode -> bce1,bce2 partials
//  Stage B1 (sigmoid(pred), halo1): Sobel -> gp min/max, S_p, S_pp; keep
//           pp[i]=prob center, gp[i]=magnitude
//  Stage B2 (dem, halo1): Sobel -> gd min/max, S_d, S_dd, S_pd;
//           Laplacian -> curvature partial; height partial (mean/istd from RF)
// 9 f64 partials {bce1,bce2,cc,ahc,S_p,S_pp,S_d,S_dd,S_pd} + 4 f32 min/max.
// grad_consistency is reconstructed in closed form later:
//   d = A_p*gp + B_p - (A_d*gd + B_d);  sum d^2 from the 5 moments.
// ---------------------------------------------------------------------------
__global__ __launch_bounds__(256) void pass1_kernel(
    const float* __restrict__ pred, const float* __restrict__ target,
    const float* __restrict__ dem, const float* __restrict__ RF,
    double* __restrict__ pD1, float* __restrict__ pF1)
{
    const int blk = blockIdx.x;
    const int img = blk >> 8;
    const int tile = blk & 255;
    const int tly = (tile >> 4) << 6;
    const int tlx = (tile & 15) << 6;
    const size_t ioff = (size_t)img * (size_t)(HH * WW);
    const float* __restrict__ tg = target + ioff;
    const float* __restrict__ pr = pred + ioff;
    const float* __restrict__ dm = dem + ioff;
    const float hmean = RF[img];
    const float histd = RF[16 + img];

    __shared__ union {
        struct {
            float t[70 * TSTR];          // target, halo 3
            unsigned char e[68 * TSTR];  // edges, halo 2
            unsigned char d[66 * TSTR];  // dilated, halo 1
        } a;
        float f[66 * TSTR];              // stage B: sigmoid(pred) then dem
    } sm;
    __shared__ double sD[9][4];
    __shared__ float sF[4][4];

    const int tid = threadIdx.x;
    const int tx = tid & 63;
    const int ty4 = tid >> 6;

    // ---- Stage A: target halo 3 (zero padded)
    for (int i = tid; i < 70 * 70; i += 256) {
        int r = i / 70, c = i - r * 70;
        int gy = tly - 3 + r, gx = tlx - 3 + c;
        float v = 0.0f;
        if ((unsigned)gy < HH && (unsigned)gx < WW) v = tg[gy * WW + gx];
        sm.a.t[r * TSTR + c] = v;
    }
    __syncthreads();
    // edges at halo 2
    for (int i = tid; i < 68 * 68; i += 256) {
        int r = i / 68, c = i - r * 68;
        int gy = tly - 2 + r, gx = tlx - 2 + c;
        unsigned char ev = 0;
        if ((unsigned)gy < HH && (unsigned)gx < WW) {
            float s = 0.0f;
#pragma unroll
            for (int dy = 0; dy < 3; dy++)
#pragma unroll
                for (int dx = 0; dx < 3; dx++)
                    s += sm.a.t[(r + dy) * TSTR + (c + dx)];
            s *= (1.0f / 9.0f);
            float cen = sm.a.t[(r + 1) * TSTR + (c + 1)];
            ev = (fabsf(cen - s) > 0.15f) ? 1 : 0;
        }
        sm.a.e[r * TSTR + c] = ev;
    }
    __syncthreads();
    // dilated at halo 1
    for (int i = tid; i < 66 * 66; i += 256) {
        int r = i / 66, c = i - r * 66;
        int gy = tly - 1 + r, gx = tlx - 1 + c;
        unsigned char dv = 0;
        if ((unsigned)gy < HH && (unsigned)gx < WW) {
            int s = 0;
#pragma unroll
            for (int dy = 0; dy < 3; dy++)
#pragma unroll
                for (int dx = 0; dx < 3; dx++)
                    s += sm.a.e[(r + dy) * TSTR + (c + dx)];
            dv = (s > 0) ? 1 : 0;
        }
        sm.a.d[r * TSTR + c] = dv;
    }
    __syncthreads();
    // interior: eroded + bce1 + bce2
    double a1 = 0.0, a2 = 0.0;
#pragma unroll
    for (int i = 0; i < 16; i++) {
        int iy = ty4 + 4 * i;
        int gy = tly + iy, gx = tlx + tx;
        int s = 0;
#pragma unroll
        for (int dy = 0; dy < 3; dy++)
#pragma unroll
            for (int dx = 0; dx < 3; dx++)
                s += sm.a.d[(iy + dy) * TSTR + (tx + dx)];
        float te = (s == 9) ? 1.0f : 0.0f;
        float tv = sm.a.t[(iy + 3) * TSTR + (tx + 3)];
        float x = pr[gy * WW + gx];
        float L = log1pf(__expf(-fabsf(x)));
        float mx = fmaxf(x, 0.0f);
        a1 += (double)(mx - x * tv + L);
        a2 += (double)(mx - x * te + L);
    }
    __syncthreads();

    // ---- Stage B1: sigmoid(pred) halo 1
    for (int i = tid; i < 66 * 66; i += 256) {
        int r = i / 66, c = i - r * 66;
        int gy = tly - 1 + r, gx = tlx - 1 + c;
        float v = 0.0f;
        if ((unsigned)gy < HH && (unsigned)gx < WW) v = sigmf(pr[gy * WW + gx]);
        sm.f[r * TSTR + c] = v;
    }
    __syncthreads();
    float pp[16], gp[16];
    float gpmin = 3.4e38f, gpmax = 0.0f;
    double S_p = 0.0, S_pp = 0.0;
#pragma unroll
    for (int i = 0; i < 16; i++) {
        int iy = ty4 + 4 * i;
        const float* b = &sm.f[iy * TSTR + tx];
        float x00 = b[0], x01 = b[1], x02 = b[2];
        float x10 = b[TSTR], x11 = b[TSTR + 1], x12 = b[TSTR + 2];
        float x20 = b[2 * TSTR], x21 = b[2 * TSTR + 1], x22 = b[2 * TSTR + 2];
        float gxv = (x02 - x00) + 2.0f * (x12 - x10) + (x22 - x20);
        float gyv = (x20 - x00) + 2.0f * (x21 - x01) + (x22 - x02);
        float g = sqrtf(gxv * gxv + gyv * gyv + 1e-8f);
        gpmin = fminf(gpmin, g);
        gpmax = fmaxf(gpmax, g);
        S_p += (double)g;
        S_pp += (double)g * (double)g;
        pp[i] = x11;
        gp[i] = g;
    }
    __syncthreads();

    // ---- Stage B2: dem halo 1
    for (int i = tid; i < 66 * 66; i += 256) {
        int r = i / 66, c = i - r * 66;
        int gy = tly - 1 + r, gx = tlx - 1 + c;
        float v = 0.0f;
        if ((unsigned)gy < HH && (unsigned)gx < WW) v = dm[gy * WW + gx];
        sm.f[r * TSTR + c] = v;
    }
    __syncthreads();
    float gdmin = 3.4e38f, gdmax = 0.0f;
    double acc = 0.0, ahc = 0.0, S_d = 0.0, S_dd = 0.0, S_pd = 0.0;
#pragma unroll
    for (int i = 0; i < 16; i++) {
        int iy = ty4 + 4 * i;
        const float* b = &sm.f[iy * TSTR + tx];
        float x00 = b[0], x01 = b[1], x02 = b[2];
        float x10 = b[TSTR], x11 = b[TSTR + 1], x12 = b[TSTR + 2];
        float x20 = b[2 * TSTR], x21 = b[2 * TSTR + 1], x22 = b[2 * TSTR + 2];
        float gxv = (x02 - x00) + 2.0f * (x12 - x10) + (x22 - x20);
        float gyv = (x20 - x00) + 2.0f * (x21 - x01) + (x22 - x02);
        float g = sqrtf(gxv * gxv + gyv * gyv + 1e-8f);
        gdmin = fminf(gdmin, g);
        gdmax = fmaxf(gdmax, g);
        S_d += (double)g;
        S_dd += (double)g * (double)g;
        S_pd += (double)gp[i] * (double)g;
        float lap = x01 + x10 + x12 + x21 - 4.0f * x11;
        float score = sigmf(tanhf(lap * 0.1f) * 10.0f);
        acc += (double)(pp[i] * score);
        float z = (x11 - hmean) * histd;
        float hn = __expf(-0.5f * z * z);
        ahc += (double)(pp[i] * hn);
    }

    // ---- block reduce partials
    double r0 = wredd(a1), r1 = wredd(a2), r2 = wredd(acc), r3 = wredd(ahc);
    double r4 = wredd(S_p), r5 = wredd(S_pp), r6 = wredd(S_d), r7 = wredd(S_dd);
    double r8 = wredd(S_pd);
    float f0 = wredminf(gpmin), f1 = wredmaxf(gpmax);
    float f2 = wredminf(gdmin), f3 = wredmaxf(gdmax);
    const int lane = tid & 63, w = tid >> 6;
    if (lane == 0) {
        sD[0][w] = r0; sD[1][w] = r1; sD[2][w] = r2; sD[3][w] = r3;
        sD[4][w] = r4; sD[5][w] = r5; sD[6][w] = r6; sD[7][w] = r7;
        sD[8][w] = r8;
        sF[0][w] = f0; sF[1][w] = f1; sF[2][w] = f2; sF[3][w] = f3;
    }
    __syncthreads();
    if (tid == 0) {
#pragma unroll
        for (int q = 0; q < 9; q++)
            pD1[q * NBLK + blk] = sD[q][0] + sD[q][1] + sD[q][2] + sD[q][3];
        pF1[0 * NBLK + blk] = fminf(fminf(sF[0][0], sF[0][1]), fminf(sF[0][2], sF[0][3]));
        pF1[1 * NBLK + blk] = fmaxf(fmaxf(sF[1][0], sF[1][1]), fmaxf(sF[1][2], sF[1][3]));
        pF1[2 * NBLK + blk] = fminf(fminf(sF[2][0], sF[2][1]), fminf(sF[2][2], sF[2][3]));
        pF1[3 * NBLK + blk] = fmaxf(fmaxf(sF[3][0], sF[3][1]), fmaxf(sF[3][2], sF[3][3]));
    }
}

// ---------------------------------------------------------------------------
// Final: reduce all partials; closed-form grad consistency; combine.
// ---------------------------------------------------------------------------
__global__ __launch_bounds__(256) void final_kernel(
    const double* __restrict__ pD1, const float* __restrict__ pF1,
    float* __restrict__ out)
{
    const int tid = threadIdx.x;
    const int lane = tid & 63, w = tid >> 6;
    __shared__ double sd[9][4];
    __shared__ float sf[4][4];

    for (int q = 0; q < 9; q++) {
        double s = 0.0;
        for (int i = tid; i < NBLK; i += 256) s += pD1[q * NBLK + i];
        s = wredd(s);
        if (lane == 0) sd[q][w] = s;
    }
    float m0 = 3.4e38f, m1 = 0.0f, m2 = 3.4e38f, m3 = 0.0f;
    for (int i = tid; i < NBLK; i += 256) {
        m0 = fminf(m0, pF1[0 * NBLK + i]);
        m1 = fmaxf(m1, pF1[1 * NBLK + i]);
        m2 = fminf(m2, pF1[2 * NBLK + i]);
        m3 = fmaxf(m3, pF1[3 * NBLK + i]);
    }
    m0 = wredminf(m0); m1 = wredmaxf(m1); m2 = wredminf(m2); m3 = wredmaxf(m3);
    if (lane == 0) { sf[0][w] = m0; sf[1][w] = m1; sf[2][w] = m2; sf[3][w] = m3; }
    __syncthreads();
    if (tid == 0) {
        double S[9];
        for (int q = 0; q < 9; q++)
            S[q] = sd[q][0] + sd[q][1] + sd[q][2] + sd[q][3];
        float gpmin = fminf(fminf(sf[0][0], sf[0][1]), fminf(sf[0][2], sf[0][3]));
        float gpmax = fmaxf(fmaxf(sf[1][0], sf[1][1]), fmaxf(sf[1][2], sf[1][3]));
        float gdmin = fminf(fminf(sf[2][0], sf[2][1]), fminf(sf[2][2], sf[2][3]));
        float gdmax = fmaxf(fmaxf(sf[3][0], sf[3][1]), fmaxf(sf[3][2], sf[3][3]));

        const double N = NTOT;
        double bce1 = S[0] / N;
        double bce2 = S[1] / N;
        double cc   = S[2] / N;   // +mean(pp*curv_score)
        double hc   = S[3] / N;   // +mean(pp*height_norm)

        // grad consistency from moments: d = Ap*gp + Bp - (Ad*gd + Bd)
        double Ap, Bp, Ad, Bd;
        if (gpmax > gpmin) {
            Ap = 1.0 / ((double)gpmax - (double)gpmin + 1e-8);
            Bp = -(double)gpmin * Ap;
        } else { Ap = 1.0; Bp = 0.0; }
        if (gdmax > gdmin) {
            Ad = 1.0 / ((double)gdmax - (double)gdmin + 1e-8);
            Bd = -(double)gdmin * Ad;
        } else { Ad = 1.0; Bd = 0.0; }
        double C = Bp - Bd;
        // S[4]=S_p S[5]=S_pp S[6]=S_d S[7]=S_dd S[8]=S_pd
        double sum_d2 = Ap * Ap * S[5] + Ad * Ad * S[7] + N * C * C
                      - 2.0 * Ap * Ad * S[8]
                      + 2.0 * Ap * C * S[4]
                      - 2.0 * Ad * C * S[6];
        double gc = sum_d2 / N;

        // total = 0.8*bce1 + 0.1*bce2 + 0.1*(gc + 0.5*(-hc) + 0.3*(-cc))
        double total = 0.8 * bce1 + 0.1 * bce2 + 0.1 * (gc - 0.5 * hc - 0.3 * cc);
        out[0] = (float)total;
    }
}

extern "C" void kernel_launch(void* const* d_in, const int* in_sizes, int n_in,
                              void* d_out, int out_size, void* d_ws, size_t ws_size,
                              hipStream_t stream)
{
    (void)in_sizes; (void)n_in; (void)out_size; (void)ws_size;
    const float* pred = (const float*)d_in[0];
    const float* target = (const float*)d_in[1];
    const float* dem = (const float*)d_in[2];
    float* out = (float*)d_out;

    // ws layout (every slot written before read each call; poison-safe):
    //   pD0 : 2*NB0 doubles   (pass0 per-image sum/sumsq partials)
    //   pD1 : 9*NBLK doubles  (pass1 partials)
    //   pF1 : 4*NBLK floats   (pass1 min/max partials)
    //   RF  : 32 floats       (per-image mean, istd)
    double* pD0 = (double*)d_ws;
    double* pD1 = pD0 + 2 * NB0;
    float*  pF1 = (float*)(pD1 + 9 * NBLK);
    float*  RF  = pF1 + 4 * NBLK;

    pass0_kernel<<<NB0, 256, 0, stream>>>(dem, pD0);
    reduce0_kernel<<<1, 64, 0, stream>>>(pD0, RF);
    pass1_kernel<<<NBLK, 256, 0, stream>>>(pred, target, dem, RF, pD1, pF1);
    final_kernel<<<1, 256, 0, stream>>>(pD1, pF1, out);
}

// Round 13
// 396.748 us; speedup vs baseline: 2.2940x; 2.2940x over previous
//
#include <hip/hip_runtime.h>
#include <math.h>

// Problem constants
#define BATCH 16
#define HH 1024
#define WW 1024
#define TSTR 72          // padded LDS row stride (no pow2 stride)
#define NBLK 4096        // 16 images * 16x16 tiles of 64x64
#define NB0 1024         // pass0 blocks (64 per image)
#define NTOT 16777216.0  // 16*1024*1024

__device__ __forceinline__ float sigmf(float x) { return 1.0f / (1.0f + __expf(-x)); }

__device__ __forceinline__ double wredd(double v) {
#pragma unroll
    for (int o = 32; o; o >>= 1) v += __shfl_down(v, o, 64);
    return v;
}
__device__ __forceinline__ float wredminf(float v) {
#pragma unroll
    for (int o = 32; o; o >>= 1) v = fminf(v, __shfl_down(v, o, 64));
    return v;
}
__device__ __forceinline__ float wredmaxf(float v) {
#pragma unroll
    for (int o = 32; o; o >>= 1) v = fmaxf(v, __shfl_down(v, o, 64));
    return v;
}

// ---------------------------------------------------------------------------
// Pass 0: stream dem, per-image sum / sumsq partials (float4 loads).
// ---------------------------------------------------------------------------
__global__ __launch_bounds__(256) void pass0_kernel(
    const float* __restrict__ dem, double* __restrict__ pD0)
{
    const int blk = blockIdx.x;
    const int tid = threadIdx.x;
    const float4* __restrict__ p =
        (const float4*)(dem + (size_t)blk * 16384);
    double s = 0.0, ss = 0.0;
    for (int i = tid; i < 4096; i += 256) {
        float4 v = p[i];
        s  += (double)v.x + (double)v.y + (double)v.z + (double)v.w;
        ss += (double)v.x * v.x + (double)v.y * v.y
            + (double)v.z * v.z + (double)v.w * v.w;
    }
    s = wredd(s); ss = wredd(ss);
    __shared__ double sh[2][4];
    const int lane = tid & 63, w = tid >> 6;
    if (lane == 0) { sh[0][w] = s; sh[1][w] = ss; }
    __syncthreads();
    if (tid == 0) {
        pD0[blk]        = sh[0][0] + sh[0][1] + sh[0][2] + sh[0][3];
        pD0[NB0 + blk]  = sh[1][0] + sh[1][1] + sh[1][2] + sh[1][3];
    }
}

// ---------------------------------------------------------------------------
// Reduce 0: per-image mean and 1/(std+eps) (unbiased), RF[0..15]=mean,
// RF[16..31]=istd.
// ---------------------------------------------------------------------------
__global__ __launch_bounds__(64) void reduce0_kernel(
    const double* __restrict__ pD0, float* __restrict__ RF)
{
    const int t = threadIdx.x;
    if (t < 16) {
        double s = 0.0, ss = 0.0;
        for (int j = 0; j < 64; j++) {
            s  += pD0[t * 64 + j];
            ss += pD0[NB0 + t * 64 + j];
        }
        const double NPI = 1048576.0;
        double mean = s / NPI;
        double var = (ss - s * s / NPI) / (NPI - 1.0);
        if (var < 0.0) var = 0.0;
        RF[t]      = (float)mean;
        RF[16 + t] = (float)(1.0 / (sqrt(var) + 1e-8));
    }
}

// ---------------------------------------------------------------------------
// Pass 1 (occupancy-tuned rewrite; r10 profile: 256 VGPR / 11.8% occ /
// VALUBusy 27% / HBM 4.4% -> latency-bound on register pressure):
//  - __launch_bounds__(256,4): cap 128 VGPR -> 4 waves/SIMD.
//  - All per-thread accumulators f32 (f64 only from wave-reduce onward).
//  - Stage B: BOTH sigmoid(pred) and dem staged in LDS simultaneously
//    (union 38 KB, 4 blocks/CU) -> one fused loop, no pp[16]/gp[16]
//    register arrays.
//  - libm tanhf/log1pf replaced with __expf/__logf forms (shorter chains).
// ---------------------------------------------------------------------------
__global__ __launch_bounds__(256, 4) void pass1_kernel(
    const float* __restrict__ pred, const float* __restrict__ target,
    const float* __restrict__ dem, const float* __restrict__ RF,
    double* __restrict__ pD1, float* __restrict__ pF1)
{
    const int blk = blockIdx.x;
    const int img = blk >> 8;
    const int tile = blk & 255;
    const int tly = (tile >> 4) << 6;
    const int tlx = (tile & 15) << 6;
    const size_t ioff = (size_t)img * (size_t)(HH * WW);
    const float* __restrict__ tg = target + ioff;
    const float* __restrict__ pr = pred + ioff;
    const float* __restrict__ dm = dem + ioff;
    const float hmean = RF[img];
    const float histd = RF[16 + img];

    __shared__ union {
        struct {
            float t[70 * TSTR];          // target, halo 3 (20160 B)
            unsigned char e[68 * TSTR];  // edges, halo 2
            unsigned char d[66 * TSTR];  // dilated, halo 1
        } a;                             // 29808 B
        struct {
            float p[66 * TSTR];          // sigmoid(pred), halo 1 (19008 B)
            float d[66 * TSTR];          // dem, halo 1 (19008 B)
        } b;                             // 38016 B
    } sm;
    __shared__ double sD[9][4];
    __shared__ float sF[4][4];

    const int tid = threadIdx.x;
    const int tx = tid & 63;
    const int ty4 = tid >> 6;

    // ---- Stage A: target halo 3 (zero padded)
    for (int i = tid; i < 70 * 70; i += 256) {
        int r = i / 70, c = i - r * 70;
        int gy = tly - 3 + r, gx = tlx - 3 + c;
        float v = 0.0f;
        if ((unsigned)gy < HH && (unsigned)gx < WW) v = tg[gy * WW + gx];
        sm.a.t[r * TSTR + c] = v;
    }
    __syncthreads();
    // edges at halo 2
    for (int i = tid; i < 68 * 68; i += 256) {
        int r = i / 68, c = i - r * 68;
        int gy = tly - 2 + r, gx = tlx - 2 + c;
        unsigned char ev = 0;
        if ((unsigned)gy < HH && (unsigned)gx < WW) {
            float s = 0.0f;
#pragma unroll
            for (int dy = 0; dy < 3; dy++)
#pragma unroll
                for (int dx = 0; dx < 3; dx++)
                    s += sm.a.t[(r + dy) * TSTR + (c + dx)];
            s *= (1.0f / 9.0f);
            float cen = sm.a.t[(r + 1) * TSTR + (c + 1)];
            ev = (fabsf(cen - s) > 0.15f) ? 1 : 0;
        }
        sm.a.e[r * TSTR + c] = ev;
    }
    __syncthreads();
    // dilated at halo 1
    for (int i = tid; i < 66 * 66; i += 256) {
        int r = i / 66, c = i - r * 66;
        int gy = tly - 1 + r, gx = tlx - 1 + c;
        unsigned char dv = 0;
        if ((unsigned)gy < HH && (unsigned)gx < WW) {
            int s = 0;
#pragma unroll
            for (int dy = 0; dy < 3; dy++)
#pragma unroll
                for (int dx = 0; dx < 3; dx++)
                    s += sm.a.e[(r + dy) * TSTR + (c + dx)];
            dv = (s > 0) ? 1 : 0;
        }
        sm.a.d[r * TSTR + c] = dv;
    }
    __syncthreads();
    // interior: eroded + bce1 + bce2 (f32 accumulation)
    float a1 = 0.0f, a2 = 0.0f;
#pragma unroll 4
    for (int i = 0; i < 16; i++) {
        int iy = ty4 + 4 * i;
        int gy = tly + iy, gx = tlx + tx;
        int s = 0;
#pragma unroll
        for (int dy = 0; dy < 3; dy++)
#pragma unroll
            for (int dx = 0; dx < 3; dx++)
                s += sm.a.d[(iy + dy) * TSTR + (tx + dx)];
        float te = (s == 9) ? 1.0f : 0.0f;
        float tv = sm.a.t[(iy + 3) * TSTR + (tx + 3)];
        float x = pr[gy * WW + gx];
        float L = __logf(1.0f + __expf(-fabsf(x)));
        float mx = fmaxf(x, 0.0f);
        a1 += mx - x * tv + L;
        a2 += mx - x * te + L;
    }
    __syncthreads();

    // ---- Stage B: stage sigmoid(pred) AND dem (halo 1) together
    for (int i = tid; i < 66 * 66; i += 256) {
        int r = i / 66, c = i - r * 66;
        int gy = tly - 1 + r, gx = tlx - 1 + c;
        float vp = 0.0f, vd = 0.0f;
        if ((unsigned)gy < HH && (unsigned)gx < WW) {
            int idx = gy * WW + gx;
            vp = sigmf(pr[idx]);
            vd = dm[idx];
        }
        sm.b.p[r * TSTR + c] = vp;
        sm.b.d[r * TSTR + c] = vd;
    }
    __syncthreads();

    float gpmin = 3.4e38f, gpmax = 0.0f, gdmin = 3.4e38f, gdmax = 0.0f;
    float aSp = 0.0f, aSpp = 0.0f, aSd = 0.0f, aSdd = 0.0f, aSpd = 0.0f;
    float a_cc = 0.0f, a_hc = 0.0f;
#pragma unroll 4
    for (int i = 0; i < 16; i++) {
        int iy = ty4 + 4 * i;
        const float* bp = &sm.b.p[iy * TSTR + tx];
        const float* bd = &sm.b.d[iy * TSTR + tx];
        // Sobel on sigmoid(pred)
        float p00 = bp[0], p01 = bp[1], p02 = bp[2];
        float p10 = bp[TSTR], p11 = bp[TSTR + 1], p12 = bp[TSTR + 2];
        float p20 = bp[2 * TSTR], p21 = bp[2 * TSTR + 1], p22 = bp[2 * TSTR + 2];
        float gxv = (p02 - p00) + 2.0f * (p12 - p10) + (p22 - p20);
        float gyv = (p20 - p00) + 2.0f * (p21 - p01) + (p22 - p02);
        float gp = sqrtf(gxv * gxv + gyv * gyv + 1e-8f);
        gpmin = fminf(gpmin, gp);
        gpmax = fmaxf(gpmax, gp);
        aSp += gp; aSpp += gp * gp;
        // Sobel + Laplacian on dem
        float d00 = bd[0], d01 = bd[1], d02 = bd[2];
        float d10 = bd[TSTR], d11 = bd[TSTR + 1], d12 = bd[TSTR + 2];
        float d20 = bd[2 * TSTR], d21 = bd[2 * TSTR + 1], d22 = bd[2 * TSTR + 2];
        float hxv = (d02 - d00) + 2.0f * (d12 - d10) + (d22 - d20);
        float hyv = (d20 - d00) + 2.0f * (d21 - d01) + (d22 - d02);
        float gd = sqrtf(hxv * hxv + hyv * hyv + 1e-8f);
        gdmin = fminf(gdmin, gd);
        gdmax = fmaxf(gdmax, gd);
        aSd += gd; aSdd += gd * gd; aSpd += gp * gd;
        // curvature: sigmoid(tanh(lap*0.1)*10), tanh via exp
        float lap = d01 + d10 + d12 + d21 - 4.0f * d11;
        float e2 = __expf(0.2f * lap);
        float th = (e2 - 1.0f) / (e2 + 1.0f);
        float score = 1.0f / (1.0f + __expf(-10.0f * th));
        a_cc += p11 * score;
        // height norm
        float z = (d11 - hmean) * histd;
        a_hc += p11 * __expf(-0.5f * z * z);
    }

    // ---- block reduce partials (widen to f64 at reduction boundary)
    double r0 = wredd((double)a1), r1 = wredd((double)a2);
    double r2 = wredd((double)a_cc), r3 = wredd((double)a_hc);
    double r4 = wredd((double)aSp), r5 = wredd((double)aSpp);
    double r6 = wredd((double)aSd), r7 = wredd((double)aSdd);
    double r8 = wredd((double)aSpd);
    float f0 = wredminf(gpmin), f1 = wredmaxf(gpmax);
    float f2 = wredminf(gdmin), f3 = wredmaxf(gdmax);
    const int lane = tid & 63, w = tid >> 6;
    if (lane == 0) {
        sD[0][w] = r0; sD[1][w] = r1; sD[2][w] = r2; sD[3][w] = r3;
        sD[4][w] = r4; sD[5][w] = r5; sD[6][w] = r6; sD[7][w] = r7;
        sD[8][w] = r8;
        sF[0][w] = f0; sF[1][w] = f1; sF[2][w] = f2; sF[3][w] = f3;
    }
    __syncthreads();
    if (tid == 0) {
#pragma unroll
        for (int q = 0; q < 9; q++)
            pD1[q * NBLK + blk] = sD[q][0] + sD[q][1] + sD[q][2] + sD[q][3];
        pF1[0 * NBLK + blk] = fminf(fminf(sF[0][0], sF[0][1]), fminf(sF[0][2], sF[0][3]));
        pF1[1 * NBLK + blk] = fmaxf(fmaxf(sF[1][0], sF[1][1]), fmaxf(sF[1][2], sF[1][3]));
        pF1[2 * NBLK + blk] = fminf(fminf(sF[2][0], sF[2][1]), fminf(sF[2][2], sF[2][3]));
        pF1[3 * NBLK + blk] = fmaxf(fmaxf(sF[3][0], sF[3][1]), fmaxf(sF[3][2], sF[3][3]));
    }
}

// ---------------------------------------------------------------------------
// Final: reduce all partials; closed-form grad consistency; combine.
// ---------------------------------------------------------------------------
__global__ __launch_bounds__(256) void final_kernel(
    const double* __restrict__ pD1, const float* __restrict__ pF1,
    float* __restrict__ out)
{
    const int tid = threadIdx.x;
    const int lane = tid & 63, w = tid >> 6;
    __shared__ double sd[9][4];
    __shared__ float sf[4][4];

    for (int q = 0; q < 9; q++) {
        double s = 0.0;
        for (int i = tid; i < NBLK; i += 256) s += pD1[q * NBLK + i];
        s = wredd(s);
        if (lane == 0) sd[q][w] = s;
    }
    float m0 = 3.4e38f, m1 = 0.0f, m2 = 3.4e38f, m3 = 0.0f;
    for (int i = tid; i < NBLK; i += 256) {
        m0 = fminf(m0, pF1[0 * NBLK + i]);
        m1 = fmaxf(m1, pF1[1 * NBLK + i]);
        m2 = fminf(m2, pF1[2 * NBLK + i]);
        m3 = fmaxf(m3, pF1[3 * NBLK + i]);
    }
    m0 = wredminf(m0); m1 = wredmaxf(m1); m2 = wredminf(m2); m3 = wredmaxf(m3);
    if (lane == 0) { sf[0][w] = m0; sf[1][w] = m1; sf[2][w] = m2; sf[3][w] = m3; }
    __syncthreads();
    if (tid == 0) {
        double S[9];
        for (int q = 0; q < 9; q++)
            S[q] = sd[q][0] + sd[q][1] + sd[q][2] + sd[q][3];
        float gpmin = fminf(fminf(sf[0][0], sf[0][1]), fminf(sf[0][2], sf[0][3]));
        float gpmax = fmaxf(fmaxf(sf[1][0], sf[1][1]), fmaxf(sf[1][2], sf[1][3]));
        float gdmin = fminf(fminf(sf[2][0], sf[2][1]), fminf(sf[2][2], sf[2][3]));
        float gdmax = fmaxf(fmaxf(sf[3][0], sf[3][1]), fmaxf(sf[3][2], sf[3][3]));

        const double N = NTOT;
        double bce1 = S[0] / N;
        double bce2 = S[1] / N;
        double cc   = S[2] / N;
        double hc   = S[3] / N;

        // grad consistency from moments: d = Ap*gp + Bp - (Ad*gd + Bd)
        double Ap, Bp, Ad, Bd;
        if (gpmax > gpmin) {
            Ap = 1.0 / ((double)gpmax - (double)gpmin + 1e-8);
            Bp = -(double)gpmin * Ap;
        } else { Ap = 1.0; Bp = 0.0; }
        if (gdmax > gdmin) {
            Ad = 1.0 / ((double)gdmax - (double)gdmin + 1e-8);
            Bd = -(double)gdmin * Ad;
        } else { Ad = 1.0; Bd = 0.0; }
        double C = Bp - Bd;
        // S[4]=S_p S[5]=S_pp S[6]=S_d S[7]=S_dd S[8]=S_pd
        double sum_d2 = Ap * Ap * S[5] + Ad * Ad * S[7] + N * C * C
                      - 2.0 * Ap * Ad * S[8]
                      + 2.0 * Ap * C * S[4]
                      - 2.0 * Ad * C * S[6];
        double gc = sum_d2 / N;

        double total = 0.8 * bce1 + 0.1 * bce2 + 0.1 * (gc - 0.5 * hc - 0.3 * cc);
        out[0] = (float)total;
    }
}

extern "C" void kernel_launch(void* const* d_in, const int* in_sizes, int n_in,
                              void* d_out, int out_size, void* d_ws, size_t ws_size,
                              hipStream_t stream)
{
    (void)in_sizes; (void)n_in; (void)out_size; (void)ws_size;
    const float* pred = (const float*)d_in[0];
    const float* target = (const float*)d_in[1];
    const float* dem = (const float*)d_in[2];
    float* out = (float*)d_out;

    // ws layout (every slot written before read each call; poison-safe):
    //   pD0 : 2*NB0 doubles   (pass0 per-image sum/sumsq partials)
    //   pD1 : 9*NBLK doubles  (pass1 partials)
    //   pF1 : 4*NBLK floats   (pass1 min/max partials)
    //   RF  : 32 floats       (per-image mean, istd)
    double* pD0 = (double*)d_ws;
    double* pD1 = pD0 + 2 * NB0;
    float*  pF1 = (float*)(pD1 + 9 * NBLK);
    float*  RF  = pF1 + 4 * NBLK;

    pass0_kernel<<<NB0, 256, 0, stream>>>(dem, pD0);
    reduce0_kernel<<<1, 64, 0, stream>>>(pD0, RF);
    pass1_kernel<<<NBLK, 256, 0, stream>>>(pred, target, dem, RF, pD1, pF1);
    final_kernel<<<1, 256, 0, stream>>>(pD1, pF1, out);
}